// Round 9
// baseline (2538.919 us; speedup 1.0000x reference)
//
#include <hip/hip_runtime.h>
#include <hip/hip_bf16.h>

#define T_STEPS 2048
#define NB      64
#define IN_DIM  300
#define HID     512

typedef __attribute__((ext_vector_type(8))) short short8;   // 8 bf16 (4 VGPR)
typedef __attribute__((ext_vector_type(4))) float f32x4;    // MFMA f32 accum
typedef __attribute__((ext_vector_type(4))) int   i32x4;    // MFMA i8 frag/accum

#define SCALE2LOG2E 2.8853900817779268f   // 2*log2(e): exp(2x) = 2^(x*SCALE2LOG2E)

static __device__ __forceinline__ unsigned short f2bf(float x) {
    unsigned int u = __float_as_uint(x);
    u = u + 0x7FFFu + ((u >> 16) & 1u);          // round-to-nearest-even
    return (unsigned short)(u >> 16);
}
static __device__ __forceinline__ unsigned cvtpk(float lo, float hi) {
    unsigned r;
    asm("v_cvt_pk_bf16_f32 %0, %1, %2" : "=v"(r) : "v"(lo), "v"(hi));
    return r;
}

// tanh+int8-quantize 4 values. x2 = cvt(acc)*sc + u2 (pre-scaled by 2log2e).
// th = 1 - 2/(2^x2+1); q = RNE(127*th) via add-magic; pack via v_perm.
static __device__ __forceinline__ unsigned tq4(const i32x4 a, const f32x4 s,
                                               unsigned w0, unsigned w1) {
    unsigned q[4];
    #pragma unroll
    for (int r = 0; r < 4; ++r) {
        const unsigned word = (r < 2) ? w0 : w1;
        const float uf = __uint_as_float((r & 1) ? (word & 0xFFFF0000u) : (word << 16));
        const float x2 = fmaf((float)a[r], s[r], uf);
        const float d = __builtin_amdgcn_exp2f(x2) + 1.f;
        q[r] = __float_as_uint(fmaf(__builtin_amdgcn_rcpf(d), -254.f, 12583039.f));
    }
    return __builtin_amdgcn_perm(
        __builtin_amdgcn_perm(q[3], q[2], 0x0C0C0400u),
        __builtin_amdgcn_perm(q[1], q[0], 0x0C0C0400u), 0x05040100u);
}

// ---------------------------------------------------------------------------
// Kernel 1: U = bf16( (x_t W_ih^T + b_ih + b_hh) * 2log2e ), rec-lane order:
// U3[t][g(4)][w(8)][lane(64)][c(4)][r(4)]  (value = pre[b=g*16+lr][j=(4w+c)*16+4lq+r])
// ---------------------------------------------------------------------------
__global__ __launch_bounds__(256, 4) void u_gemm(
    const float* __restrict__ X, const float* __restrict__ Wih,
    const float* __restrict__ bih, const float* __restrict__ bhh,
    unsigned short* __restrict__ U3)
{
    __shared__ unsigned short As[64 * 160];   // X rows (batch m)
    __shared__ unsigned short Bs[64 * 160];   // Wih rows (j)
    const int tid = threadIdx.x;
    const int m0 = (blockIdx.x >> 3) * 64, n0 = (blockIdx.x & 7) * 64;
    const int w = tid >> 6, l = tid & 63;
    const int lq = l >> 4, lr = l & 15;

    const f32x4 zv = {0.f, 0.f, 0.f, 0.f};
    f32x4 acc[2][2] = {{zv, zv}, {zv, zv}};   // [jt][mt]

    for (int kh = 0; kh < 2; ++kh) {
        const int kbase = kh * 160;
        __syncthreads();
        for (int i = tid; i < 64 * 40; i += 256) {
            const int r = i / 40, q = i - r * 40;
            const int kg = kbase + q * 4;
            unsigned int a0 = 0, a1 = 0, b0 = 0, b1 = 0;
            if (kg + 4 <= IN_DIM) {
                const float4 v = *reinterpret_cast<const float4*>(X + (size_t)(m0 + r) * IN_DIM + kg);
                a0 = (unsigned)f2bf(v.x) | ((unsigned)f2bf(v.y) << 16);
                a1 = (unsigned)f2bf(v.z) | ((unsigned)f2bf(v.w) << 16);
                const float4 u = *reinterpret_cast<const float4*>(Wih + (size_t)(n0 + r) * IN_DIM + kg);
                b0 = (unsigned)f2bf(u.x) | ((unsigned)f2bf(u.y) << 16);
                b1 = (unsigned)f2bf(u.z) | ((unsigned)f2bf(u.w) << 16);
            }
            int byte = r * 320 + q * 8; byte ^= ((r & 7) << 4);
            *reinterpret_cast<uint2*>(reinterpret_cast<char*>(As) + byte) = make_uint2(a0, a1);
            *reinterpret_cast<uint2*>(reinterpret_cast<char*>(Bs) + byte) = make_uint2(b0, b1);
        }
        __syncthreads();
        #pragma unroll
        for (int kc = 0; kc < 5; ++kc) {
            const int koff = kc * 64 + lq * 16;
            short8 xa[2], wb[2];
            #pragma unroll
            for (int mt = 0; mt < 2; ++mt) {
                const int row = (w >> 1) * 32 + mt * 16 + lr;       // X row (m)
                int abyte = row * 320 + koff; abyte ^= ((row & 7) << 4);
                xa[mt] = *reinterpret_cast<const short8*>(reinterpret_cast<const char*>(As) + abyte);
                const int jrow = (w & 1) * 32 + mt * 16 + lr;       // W row (j)
                int bbyte = jrow * 320 + koff; bbyte ^= ((jrow & 7) << 4);
                wb[mt] = *reinterpret_cast<const short8*>(reinterpret_cast<const char*>(Bs) + bbyte);
            }
            #pragma unroll
            for (int jt = 0; jt < 2; ++jt)
                #pragma unroll
                for (int mt = 0; mt < 2; ++mt)
                    acc[jt][mt] = __builtin_amdgcn_mfma_f32_16x16x32_bf16(
                        wb[jt], xa[mt], acc[jt][mt], 0, 0, 0);
        }
    }
    const int t = blockIdx.x >> 3;
    #pragma unroll
    for (int jt = 0; jt < 2; ++jt) {
        const int jb = n0 + (w & 1) * 32 + jt * 16 + 4 * lq;        // 4 consecutive j
        const float4 b1v = *reinterpret_cast<const float4*>(bih + jb);
        const float4 b2v = *reinterpret_cast<const float4*>(bhh + jb);
        const float4 bv = {(b1v.x + b2v.x) * SCALE2LOG2E, (b1v.y + b2v.y) * SCALE2LOG2E,
                           (b1v.z + b2v.z) * SCALE2LOG2E, (b1v.w + b2v.w) * SCALE2LOG2E};
        const int jtg = jb >> 4;
        const int wv2 = jtg >> 2, cc = jtg & 3;
        #pragma unroll
        for (int mt = 0; mt < 2; ++mt) {
            const int b = (w >> 1) * 32 + mt * 16 + lr;             // batch row
            const int g = b >> 4, lrr = b & 15;
            const f32x4 a = acc[jt][mt];
            uint2 p;
            p.x = cvtpk(fmaf(a[0], SCALE2LOG2E, bv.x), fmaf(a[1], SCALE2LOG2E, bv.y));
            p.y = cvtpk(fmaf(a[2], SCALE2LOG2E, bv.z), fmaf(a[3], SCALE2LOG2E, bv.w));
            const size_t sidx = ((((size_t)t * 4 + g) * 8 + wv2) * 64 + (lq * 16 + lrr)) * 16 + cc * 4;
            *reinterpret_cast<uint2*>(U3 + sidx) = p;
        }
    }
}

// ---------------------------------------------------------------------------
// Kernel 2: int8 recurrence with SKEWED half-step schedule. 4 blocks x 512thr.
// lo waves (0-3) own cols 0..255 (k-chunks 0..3); hi waves (4-7) cols 256..511.
// Phase A: M1(t) [kt 0..3, reads h(t).lo]; HI waves also tanh(acc(t-1)) ->
//   write h(t).hi -- VALU hidden under M1's matrix work (lo wave on same SIMD
//   is pure-MFMA). b2. Phase B: M2(t) [kt 4..7] completes acc(t); LO waves
//   tanh -> h(t+1).lo. b1. Register ping-pong (2-step unroll) for acc/U sets.
// ---------------------------------------------------------------------------
__global__ __launch_bounds__(512) __attribute__((amdgpu_waves_per_eu(2, 2)))
void rnn_rec(const float* __restrict__ Whh, const unsigned short* __restrict__ U3,
             float* __restrict__ out)
{
    const int g = blockIdx.x;                // 0..3
    const int tid = threadIdx.x;
    const int w = tid >> 6, l = tid & 63;
    const int lq = l >> 4, lr = l & 15;
    const bool HI = (w >= 4);

    __shared__ char h8[2 * 16 * 512];        // [parity][m][k] swizzled
    __shared__ float wsc_lds[512];           // per-j scale (pre-scaled by 2log2e)

    // ---- one-time: quantize W to registers (static-indexed) ----
    i32x4 wq[4][8];
    #pragma unroll
    for (int c = 0; c < 4; ++c) {
        const float* wr = Whh + (size_t)((4 * w + c) * 16 + lr) * HID;
        float amax = 0.f;
        #pragma unroll
        for (int kt = 0; kt < 8; ++kt) {
            const int k0 = kt * 64 + lq * 16;
            #pragma unroll
            for (int q4 = 0; q4 < 4; ++q4) {
                const float4 v = *reinterpret_cast<const float4*>(wr + k0 + q4 * 4);
                amax = fmaxf(amax, fmaxf(fmaxf(fabsf(v.x), fabsf(v.y)),
                                         fmaxf(fabsf(v.z), fabsf(v.w))));
            }
        }
        amax = fmaxf(amax, __shfl_xor(amax, 16));
        amax = fmaxf(amax, __shfl_xor(amax, 32));    // full-row max
        const float inv = 127.f / amax;
        #pragma unroll
        for (int kt = 0; kt < 8; ++kt) {
            const int k0 = kt * 64 + lq * 16;
            i32x4 pk;
            #pragma unroll
            for (int q4 = 0; q4 < 4; ++q4) {
                const float4 v = *reinterpret_cast<const float4*>(wr + k0 + q4 * 4);
                const int q0 = (int)rintf(v.x * inv), q1 = (int)rintf(v.y * inv);
                const int q2 = (int)rintf(v.z * inv), q3 = (int)rintf(v.w * inv);
                pk[q4] = (q0 & 255) | ((q1 & 255) << 8) | ((q2 & 255) << 16) | (q3 << 24);
            }
            wq[c][kt] = pk;
        }
        if (lq == 0)
            wsc_lds[(4 * w + c) * 16 + lr] = amax * (SCALE2LOG2E / 16129.f);
    }
    // ---- h0 = 0 (both parities) ----
    for (int i = tid * 32; i < 2 * 16 * 512; i += 512 * 32) {
        *reinterpret_cast<uint4*>(h8 + i) = make_uint4(0, 0, 0, 0);
        *reinterpret_cast<uint4*>(h8 + i + 16) = make_uint4(0, 0, 0, 0);
    }
    __syncthreads();

    // per-lane D-column scales: j = (4w+c)*16 + 4lq + r
    f32x4 sc2[4];
    #pragma unroll
    for (int c = 0; c < 4; ++c) {
        const float4 s = *reinterpret_cast<const float4*>(&wsc_lds[(4 * w + c) * 16 + 4 * lq]);
        sc2[c] = f32x4{s.x, s.y, s.z, s.w};
    }

    // ---- t-invariant addresses ----
    const int swz = (lr & 7) << 4;
    const int rrow = lr * 512;
    const int lq16 = lq * 16;
    const int swz_lo = swz & 48, s64 = swz & 64;
    const int hvE = rrow + (lq16 ^ swz_lo) + s64;          // even kt: +kt*64 imm
    const int hvO = rrow + (lq16 ^ swz_lo) + (64 ^ s64);   // odd  kt: +(kt-1)*64
    int wrA[4];
    #pragma unroll
    for (int c = 0; c < 4; ++c)
        wrA[c] = rrow + ((((4 * w + c) * 16) + 4 * lq) ^ swz);
    const char* h8c = h8;
    char* h8w = h8;

    const unsigned short* uptr = U3 + ((size_t)(g * 8 + w) * 64 + l) * 16;
    const i32x4 ZER = {0, 0, 0, 0};
    uint4 uXa = {0,0,0,0}, uXb = {0,0,0,0}, uYa = {0,0,0,0}, uYb = {0,0,0,0};
    i32x4 aX0 = ZER, aX1 = ZER, aX2 = ZER, aX3 = ZER;
    i32x4 aY0 = ZER, aY1 = ZER, aY2 = ZER, aY3 = ZER;

#define MFMA_I8(W_, H_, A_) __builtin_amdgcn_mfma_i32_16x16x64_i8(W_, H_, A_, 0, 0, 0)

#define STEP(PAR, A0,A1,A2,A3, P0,P1,P2,P3, UCa,UCb, UPa,UPb, DOTHI)           \
    {                                                                          \
        UCa = *reinterpret_cast<const uint4*>(uptr);                           \
        UCb = *reinterpret_cast<const uint4*>(uptr + 8);                       \
        uptr += 32768;                                                         \
        const char* rb_ = h8c + (PAR) * 8192;                                  \
        char* wa_ = h8w + (PAR) * 8192;                                        \
        char* wb_ = h8w + ((PAR) ^ 1) * 8192;                                  \
        { /* phase A: M1 (kt 0..3); HI also T_hi(prev) -> h(t).hi */           \
            const i32x4 h0 = *reinterpret_cast<const i32x4*>(rb_ + hvE);       \
            const i32x4 h1 = *reinterpret_cast<const i32x4*>(rb_ + hvO);       \
            const i32x4 h2 = *reinterpret_cast<const i32x4*>(rb_ + hvE + 128); \
            const i32x4 h3 = *reinterpret_cast<const i32x4*>(rb_ + hvO + 128); \
            A0 = MFMA_I8(wq[0][0], h0, ZER); A1 = MFMA_I8(wq[1][0], h0, ZER);  \
            A2 = MFMA_I8(wq[2][0], h0, ZER); A3 = MFMA_I8(wq[3][0], h0, ZER);  \
            if (DOTHI && HI) {                                                 \
                *reinterpret_cast<unsigned*>(wa_ + wrA[0]) = tq4(P0, sc2[0], UPa.x, UPa.y); \
                *reinterpret_cast<unsigned*>(wa_ + wrA[1]) = tq4(P1, sc2[1], UPa.z, UPa.w); \
            }                                                                  \
            A0 = MFMA_I8(wq[0][1], h1, A0); A1 = MFMA_I8(wq[1][1], h1, A1);    \
            A2 = MFMA_I8(wq[2][1], h1, A2); A3 = MFMA_I8(wq[3][1], h1, A3);    \
            if (DOTHI && HI) {                                                 \
                *reinterpret_cast<unsigned*>(wa_ + wrA[2]) = tq4(P2, sc2[2], UPb.x, UPb.y); \
                *reinterpret_cast<unsigned*>(wa_ + wrA[3]) = tq4(P3, sc2[3], UPb.z, UPb.w); \
            }                                                                  \
            A0 = MFMA_I8(wq[0][2], h2, A0); A1 = MFMA_I8(wq[1][2], h2, A1);    \
            A2 = MFMA_I8(wq[2][2], h2, A2); A3 = MFMA_I8(wq[3][2], h2, A3);    \
            A0 = MFMA_I8(wq[0][3], h3, A0); A1 = MFMA_I8(wq[1][3], h3, A1);    \
            A2 = MFMA_I8(wq[2][3], h3, A2); A3 = MFMA_I8(wq[3][3], h3, A3);    \
        }                                                                      \
        __syncthreads();   /* b2: h(t).hi written; M1 reads done */            \
        { /* phase B: M2 (kt 4..7) -> acc complete; LO: T_lo -> h(t+1).lo */   \
            const i32x4 h4 = *reinterpret_cast<const i32x4*>(rb_ + hvE + 256); \
            const i32x4 h5 = *reinterpret_cast<const i32x4*>(rb_ + hvO + 256); \
            const i32x4 h6 = *reinterpret_cast<const i32x4*>(rb_ + hvE + 384); \
            const i32x4 h7 = *reinterpret_cast<const i32x4*>(rb_ + hvO + 384); \
            A0 = MFMA_I8(wq[0][4], h4, A0); A1 = MFMA_I8(wq[1][4], h4, A1);    \
            A2 = MFMA_I8(wq[2][4], h4, A2); A3 = MFMA_I8(wq[3][4], h4, A3);    \
            A0 = MFMA_I8(wq[0][5], h5, A0); A1 = MFMA_I8(wq[1][5], h5, A1);    \
            A2 = MFMA_I8(wq[2][5], h5, A2); A3 = MFMA_I8(wq[3][5], h5, A3);    \
            A0 = MFMA_I8(wq[0][6], h6, A0); A1 = MFMA_I8(wq[1][6], h6, A1);    \
            A2 = MFMA_I8(wq[2][6], h6, A2); A3 = MFMA_I8(wq[3][6], h6, A3);    \
            A0 = MFMA_I8(wq[0][7], h7, A0); A1 = MFMA_I8(wq[1][7], h7, A1);    \
            A2 = MFMA_I8(wq[2][7], h7, A2); A3 = MFMA_I8(wq[3][7], h7, A3);    \
        }                                                                      \
        if (!HI) {                                                             \
            *reinterpret_cast<unsigned*>(wb_ + wrA[0]) = tq4(A0, sc2[0], UCa.x, UCa.y); \
            *reinterpret_cast<unsigned*>(wb_ + wrA[1]) = tq4(A1, sc2[1], UCa.z, UCa.w); \
            *reinterpret_cast<unsigned*>(wb_ + wrA[2]) = tq4(A2, sc2[2], UCb.x, UCb.y); \
            *reinterpret_cast<unsigned*>(wb_ + wrA[3]) = tq4(A3, sc2[3], UCb.z, UCb.w); \
        }                                                                      \
        __syncthreads();   /* b1: h(t+1).lo written; M2 reads done */          \
    }

    // ---- peel t = 0 (no pending T_hi) ----
    STEP(0, aX0,aX1,aX2,aX3, aY0,aY1,aY2,aY3, uXa,uXb, uYa,uYb, 0)

    // ---- main loop: t = 1..2046 (1023 x 2 steps) ----
    #pragma unroll 1
    for (int it = 0; it < 1023; ++it) {
        STEP(1, aY0,aY1,aY2,aY3, aX0,aX1,aX2,aX3, uYa,uYb, uXa,uXb, 1)  // odd t
        STEP(0, aX0,aX1,aX2,aX3, aY0,aY1,aY2,aY3, uXa,uXb, uYa,uYb, 1)  // even t
    }

    // ---- epilogue t = 2047 (PAR=1): flush T_hi(2046), final MFMA, f32 out --
    {
        uYa = *reinterpret_cast<const uint4*>(uptr);
        uYb = *reinterpret_cast<const uint4*>(uptr + 8);
        const char* rb_ = h8c + 8192;
        char* wa_ = h8w + 8192;
        if (HI) {
            *reinterpret_cast<unsigned*>(wa_ + wrA[0]) = tq4(aX0, sc2[0], uXa.x, uXa.y);
            *reinterpret_cast<unsigned*>(wa_ + wrA[1]) = tq4(aX1, sc2[1], uXa.z, uXa.w);
            *reinterpret_cast<unsigned*>(wa_ + wrA[2]) = tq4(aX2, sc2[2], uXb.x, uXb.y);
            *reinterpret_cast<unsigned*>(wa_ + wrA[3]) = tq4(aX3, sc2[3], uXb.z, uXb.w);
        }
        {
            const i32x4 h0 = *reinterpret_cast<const i32x4*>(rb_ + hvE);
            const i32x4 h1 = *reinterpret_cast<const i32x4*>(rb_ + hvO);
            const i32x4 h2 = *reinterpret_cast<const i32x4*>(rb_ + hvE + 128);
            const i32x4 h3 = *reinterpret_cast<const i32x4*>(rb_ + hvO + 128);
            aY0 = MFMA_I8(wq[0][0], h0, ZER); aY1 = MFMA_I8(wq[1][0], h0, ZER);
            aY2 = MFMA_I8(wq[2][0], h0, ZER); aY3 = MFMA_I8(wq[3][0], h0, ZER);
            aY0 = MFMA_I8(wq[0][1], h1, aY0); aY1 = MFMA_I8(wq[1][1], h1, aY1);
            aY2 = MFMA_I8(wq[2][1], h1, aY2); aY3 = MFMA_I8(wq[3][1], h1, aY3);
            aY0 = MFMA_I8(wq[0][2], h2, aY0); aY1 = MFMA_I8(wq[1][2], h2, aY1);
            aY2 = MFMA_I8(wq[2][2], h2, aY2); aY3 = MFMA_I8(wq[3][2], h2, aY3);
            aY0 = MFMA_I8(wq[0][3], h3, aY0); aY1 = MFMA_I8(wq[1][3], h3, aY1);
            aY2 = MFMA_I8(wq[2][3], h3, aY2); aY3 = MFMA_I8(wq[3][3], h3, aY3);
        }
        __syncthreads();
        {
            const i32x4 h4 = *reinterpret_cast<const i32x4*>(rb_ + hvE + 256);
            const i32x4 h5 = *reinterpret_cast<const i32x4*>(rb_ + hvO + 256);
            const i32x4 h6 = *reinterpret_cast<const i32x4*>(rb_ + hvE + 384);
            const i32x4 h7 = *reinterpret_cast<const i32x4*>(rb_ + hvO + 384);
            aY0 = MFMA_I8(wq[0][4], h4, aY0); aY1 = MFMA_I8(wq[1][4], h4, aY1);
            aY2 = MFMA_I8(wq[2][4], h4, aY2); aY3 = MFMA_I8(wq[3][4], h4, aY3);
            aY0 = MFMA_I8(wq[0][5], h5, aY0); aY1 = MFMA_I8(wq[1][5], h5, aY1);
            aY2 = MFMA_I8(wq[2][5], h5, aY2); aY3 = MFMA_I8(wq[3][5], h5, aY3);
            aY0 = MFMA_I8(wq[0][6], h6, aY0); aY1 = MFMA_I8(wq[1][6], h6, aY1);
            aY2 = MFMA_I8(wq[2][6], h6, aY2); aY3 = MFMA_I8(wq[3][6], h6, aY3);
            aY0 = MFMA_I8(wq[0][7], h7, aY0); aY1 = MFMA_I8(wq[1][7], h7, aY1);
            aY2 = MFMA_I8(wq[2][7], h7, aY2); aY3 = MFMA_I8(wq[3][7], h7, aY3);
        }
        #pragma unroll
        for (int c = 0; c < 4; ++c) {
            const i32x4 a = (c == 0) ? aY0 : (c == 1) ? aY1 : (c == 2) ? aY2 : aY3;
            const unsigned w0 = (c == 0) ? uYa.x : (c == 1) ? uYa.z : (c == 2) ? uYb.x : uYb.z;
            const unsigned w1 = (c == 0) ? uYa.y : (c == 1) ? uYa.w : (c == 2) ? uYb.y : uYb.w;
            float th[4];
            #pragma unroll
            for (int r = 0; r < 4; ++r) {
                const unsigned word = (r < 2) ? w0 : w1;
                const float uf = __uint_as_float((r & 1) ? (word & 0xFFFF0000u) : (word << 16));
                const float x2 = fmaf((float)a[r], sc2[c][r], uf);
                const float d = __builtin_amdgcn_exp2f(x2) + 1.f;
                th[r] = fmaf(__builtin_amdgcn_rcpf(d), -2.f, 1.f);
            }
            const float4 o = {th[0], th[1], th[2], th[3]};
            *reinterpret_cast<float4*>(out + (size_t)(g * 16 + lr) * HID +
                                       (4 * w + c) * 16 + 4 * lq) = o;
        }
    }
#undef STEP
#undef MFMA_I8
}

// ---------------------------------------------------------------------------
extern "C" void kernel_launch(void* const* d_in, const int* in_sizes, int n_in,
                              void* d_out, int out_size, void* d_ws, size_t ws_size,
                              hipStream_t stream) {
    const float* X   = (const float*)d_in[0];   // [2048][64][300]
    const float* Wih = (const float*)d_in[1];   // [512][300]
    const float* Whh = (const float*)d_in[2];   // [512][512]
    const float* bih = (const float*)d_in[3];   // [512]
    const float* bhh = (const float*)d_in[4];   // [512]
    float* out = (float*)d_out;                 // [64][512]
    unsigned short* U3 = (unsigned short*)d_ws; // 128 MB, rec-lane order

    u_gemm<<<dim3(2048 * 8), dim3(256), 0, stream>>>(X, Wih, bih, bhh, U3);
    rnn_rec<<<dim3(4), dim3(512), 0, stream>>>(Whh, U3, out);
}

// Round 10
// 2430.261 us; speedup vs baseline: 1.0447x; 1.0447x over previous
//
#include <hip/hip_runtime.h>
#include <hip/hip_bf16.h>

#define T_STEPS 2048
#define NB      64
#define IN_DIM  300
#define HID     512

typedef __attribute__((ext_vector_type(8))) short short8;   // 8 bf16 (4 VGPR)
typedef __attribute__((ext_vector_type(4))) float f32x4;    // MFMA f32 accum
typedef __attribute__((ext_vector_type(4))) int   i32x4;    // MFMA i8 frag/accum

#define SCALE2LOG2E 2.8853900817779268f       // 2*log2(e)
#define USCALE      369.33000f                // 2*log2(e)*128 (table fixed-point)

static __device__ __forceinline__ unsigned short f2bf(float x) {
    unsigned int u = __float_as_uint(x);
    u = u + 0x7FFFu + ((u >> 16) & 1u);          // round-to-nearest-even
    return (unsigned short)(u >> 16);
}
static __device__ __forceinline__ unsigned cvtpk(float lo, float hi) {
    unsigned r;
    asm("v_cvt_pk_bf16_f32 %0, %1, %2" : "=v"(r) : "v"(lo), "v"(hi));
    return r;
}

// tanh+int8-quantize 4 values via LDS table. xi = cvt(acc)*sc + u (both
// pre-scaled by 2log2e*128) + 2^23*1.5 -> low 12 mantissa bits = two's-compl
// fixed-point index. fmed3 clamps to table range. ZERO transcendentals.
static __device__ __forceinline__ unsigned tq4t(const i32x4 a, const f32x4 s,
                                                unsigned w0, unsigned w1,
                                                const unsigned char* tab) {
    unsigned q[4];
    #pragma unroll
    for (int r = 0; r < 4; ++r) {
        const unsigned word = (r < 2) ? w0 : w1;
        const float uf = __uint_as_float((r & 1) ? (word & 0xFFFF0000u) : (word << 16));
        const float xi = fmaf((float)a[r], s[r], uf) + 12582912.f;   // 2^23*1.5
        const float xc = __builtin_amdgcn_fmed3f(xi, 12580864.f, 12584959.f);
        q[r] = tab[__float_as_uint(xc) & 0xFFFu];                    // ds_read_u8
    }
    return __builtin_amdgcn_perm(
        __builtin_amdgcn_perm(q[3], q[2], 0x0C0C0400u),
        __builtin_amdgcn_perm(q[1], q[0], 0x0C0C0400u), 0x05040100u);
}

// ---------------------------------------------------------------------------
// Kernel 1: U = bf16( (x_t W_ih^T + b_ih + b_hh) * 2log2e*128 ), rec-lane
// order: U3[t][g(4)][w(8)][lane(64)][c(4)][r(4)]
//   (value = pre[b=g*16+lr][j=(4w+c)*16+4*lq+r])
// ---------------------------------------------------------------------------
__global__ __launch_bounds__(256, 4) void u_gemm(
    const float* __restrict__ X, const float* __restrict__ Wih,
    const float* __restrict__ bih, const float* __restrict__ bhh,
    unsigned short* __restrict__ U3)
{
    __shared__ unsigned short As[64 * 160];   // X rows (batch m)
    __shared__ unsigned short Bs[64 * 160];   // Wih rows (j)
    const int tid = threadIdx.x;
    const int m0 = (blockIdx.x >> 3) * 64, n0 = (blockIdx.x & 7) * 64;
    const int w = tid >> 6, l = tid & 63;
    const int lq = l >> 4, lr = l & 15;

    const f32x4 zv = {0.f, 0.f, 0.f, 0.f};
    f32x4 acc[2][2] = {{zv, zv}, {zv, zv}};   // [jt][mt]

    for (int kh = 0; kh < 2; ++kh) {
        const int kbase = kh * 160;
        __syncthreads();
        for (int i = tid; i < 64 * 40; i += 256) {
            const int r = i / 40, q = i - r * 40;
            const int kg = kbase + q * 4;
            unsigned int a0 = 0, a1 = 0, b0 = 0, b1 = 0;
            if (kg + 4 <= IN_DIM) {
                const float4 v = *reinterpret_cast<const float4*>(X + (size_t)(m0 + r) * IN_DIM + kg);
                a0 = (unsigned)f2bf(v.x) | ((unsigned)f2bf(v.y) << 16);
                a1 = (unsigned)f2bf(v.z) | ((unsigned)f2bf(v.w) << 16);
                const float4 u = *reinterpret_cast<const float4*>(Wih + (size_t)(n0 + r) * IN_DIM + kg);
                b0 = (unsigned)f2bf(u.x) | ((unsigned)f2bf(u.y) << 16);
                b1 = (unsigned)f2bf(u.z) | ((unsigned)f2bf(u.w) << 16);
            }
            int byte = r * 320 + q * 8; byte ^= ((r & 7) << 4);
            *reinterpret_cast<uint2*>(reinterpret_cast<char*>(As) + byte) = make_uint2(a0, a1);
            *reinterpret_cast<uint2*>(reinterpret_cast<char*>(Bs) + byte) = make_uint2(b0, b1);
        }
        __syncthreads();
        #pragma unroll
        for (int kc = 0; kc < 5; ++kc) {
            const int koff = kc * 64 + lq * 16;
            short8 xa[2], wb[2];
            #pragma unroll
            for (int mt = 0; mt < 2; ++mt) {
                const int row = (w >> 1) * 32 + mt * 16 + lr;       // X row (m)
                int abyte = row * 320 + koff; abyte ^= ((row & 7) << 4);
                xa[mt] = *reinterpret_cast<const short8*>(reinterpret_cast<const char*>(As) + abyte);
                const int jrow = (w & 1) * 32 + mt * 16 + lr;       // W row (j)
                int bbyte = jrow * 320 + koff; bbyte ^= ((jrow & 7) << 4);
                wb[mt] = *reinterpret_cast<const short8*>(reinterpret_cast<const char*>(Bs) + bbyte);
            }
            #pragma unroll
            for (int jt = 0; jt < 2; ++jt)
                #pragma unroll
                for (int mt = 0; mt < 2; ++mt)
                    acc[jt][mt] = __builtin_amdgcn_mfma_f32_16x16x32_bf16(
                        wb[jt], xa[mt], acc[jt][mt], 0, 0, 0);
        }
    }
    const int t = blockIdx.x >> 3;
    #pragma unroll
    for (int jt = 0; jt < 2; ++jt) {
        const int jb = n0 + (w & 1) * 32 + jt * 16 + 4 * lq;        // 4 consecutive j
        const float4 b1v = *reinterpret_cast<const float4*>(bih + jb);
        const float4 b2v = *reinterpret_cast<const float4*>(bhh + jb);
        const float4 bv = {(b1v.x + b2v.x) * USCALE, (b1v.y + b2v.y) * USCALE,
                           (b1v.z + b2v.z) * USCALE, (b1v.w + b2v.w) * USCALE};
        const int jtg = jb >> 4;
        const int wv2 = jtg >> 2, cc = jtg & 3;
        #pragma unroll
        for (int mt = 0; mt < 2; ++mt) {
            const int b = (w >> 1) * 32 + mt * 16 + lr;             // batch row
            const int g = b >> 4, lrr = b & 15;
            const f32x4 a = acc[jt][mt];
            uint2 p;
            p.x = cvtpk(fmaf(a[0], USCALE, bv.x), fmaf(a[1], USCALE, bv.y));
            p.y = cvtpk(fmaf(a[2], USCALE, bv.z), fmaf(a[3], USCALE, bv.w));
            const size_t sidx = ((((size_t)t * 4 + g) * 8 + wv2) * 64 + (lq * 16 + lrr)) * 16 + cc * 4;
            *reinterpret_cast<uint2*>(U3 + sidx) = p;
        }
    }
}

// ---------------------------------------------------------------------------
// Kernel 2: int8 recurrence (R7 skeleton). 4 blocks x 512 thr. W register-
// stationary (wq[4][8], static idx). Per step: 8 ds_read_b128 -> hv[8],
// 32 i8-MFMA (4 chains), tanh+quant via 4KB LDS TABLE (6 VALU + 1 ds_u8 per
// value, zero transcendentals), 1 barrier/step, parity-dbuf h.
// ---------------------------------------------------------------------------
__global__ __launch_bounds__(512) __attribute__((amdgpu_waves_per_eu(2, 2)))
void rnn_rec(const float* __restrict__ Whh, const unsigned short* __restrict__ U3,
             float* __restrict__ out)
{
    const int g = blockIdx.x;                // 0..3
    const int tid = threadIdx.x;
    const int w = tid >> 6, l = tid & 63;
    const int lq = l >> 4, lr = l & 15;

    __shared__ char h8[2 * 16 * 512];        // [parity][m][k] swizzled
    __shared__ float wsc_lds[512];           // per-j scale (pre-scaled)
    __shared__ unsigned char ttab[4096];     // tanh+quant table (2's-compl idx)

    // ---- one-time: tanh table (idx = two's-complement of x2*128) ----
    for (int i = tid; i < 4096; i += 512) {
        const int v = (i < 2048) ? i : i - 4096;
        const float x2 = (float)v * 0.0078125f;          // /128
        const float e = __builtin_amdgcn_exp2f(x2);
        const float th = (e - 1.f) / (e + 1.f);          // tanh(x2*ln2/2)
        ttab[i] = (unsigned char)(int)rintf(127.f * th);
    }

    // ---- one-time: quantize W to registers (static-indexed) ----
    i32x4 wq[4][8];
    #pragma unroll
    for (int c = 0; c < 4; ++c) {
        const float* wr = Whh + (size_t)((4 * w + c) * 16 + lr) * HID;
        float amax = 0.f;
        #pragma unroll
        for (int kt = 0; kt < 8; ++kt) {
            const int k0 = kt * 64 + lq * 16;
            #pragma unroll
            for (int q4 = 0; q4 < 4; ++q4) {
                const float4 v = *reinterpret_cast<const float4*>(wr + k0 + q4 * 4);
                amax = fmaxf(amax, fmaxf(fmaxf(fabsf(v.x), fabsf(v.y)),
                                         fmaxf(fabsf(v.z), fabsf(v.w))));
            }
        }
        amax = fmaxf(amax, __shfl_xor(amax, 16));
        amax = fmaxf(amax, __shfl_xor(amax, 32));    // full-row max
        const float inv = 127.f / amax;
        #pragma unroll
        for (int kt = 0; kt < 8; ++kt) {
            const int k0 = kt * 64 + lq * 16;
            i32x4 pk;
            #pragma unroll
            for (int q4 = 0; q4 < 4; ++q4) {
                const float4 v = *reinterpret_cast<const float4*>(wr + k0 + q4 * 4);
                const int q0 = (int)rintf(v.x * inv), q1 = (int)rintf(v.y * inv);
                const int q2 = (int)rintf(v.z * inv), q3 = (int)rintf(v.w * inv);
                pk[q4] = (q0 & 255) | ((q1 & 255) << 8) | ((q2 & 255) << 16) | (q3 << 24);
            }
            wq[c][kt] = pk;
        }
        if (lq == 0)
            wsc_lds[(4 * w + c) * 16 + lr] = amax * (USCALE / 16129.f);
    }
    // ---- h0 = 0 (both parities) ----
    for (int i = tid * 32; i < 2 * 16 * 512; i += 512 * 32) {
        *reinterpret_cast<uint4*>(h8 + i) = make_uint4(0, 0, 0, 0);
        *reinterpret_cast<uint4*>(h8 + i + 16) = make_uint4(0, 0, 0, 0);
    }
    __syncthreads();

    // per-lane D-column scales: j = (4w+c)*16 + 4lq + r
    f32x4 sc2[4];
    #pragma unroll
    for (int c = 0; c < 4; ++c) {
        const float4 s = *reinterpret_cast<const float4*>(&wsc_lds[(4 * w + c) * 16 + 4 * lq]);
        sc2[c] = f32x4{s.x, s.y, s.z, s.w};
    }

    const int swz = (lr & 7) << 4;
    const int rrow = lr * 512;
    const int lq16 = lq * 16;
    int wrA[4];
    #pragma unroll
    for (int c = 0; c < 4; ++c)
        wrA[c] = rrow + ((((4 * w + c) * 16) + 4 * lq) ^ swz);

    const unsigned short* ub = U3 + ((size_t)(g * 8 + w) * 64 + l) * 16;
    uint4 uA0 = *reinterpret_cast<const uint4*>(ub);
    uint4 uB0 = *reinterpret_cast<const uint4*>(ub + 8);
    const unsigned short* uptr = ub + 32768;
    uint4 uA1, uB1;

#define MFMA_I8(W_, H_, A_) __builtin_amdgcn_mfma_i32_16x16x64_i8(W_, H_, A_, 0, 0, 0)

#define RSTEP(T_, UA, UB, UAN, UBN)                                            \
    {                                                                          \
        UAN = *reinterpret_cast<const uint4*>(uptr);                           \
        UBN = *reinterpret_cast<const uint4*>(uptr + 8);                       \
        uptr += 32768;                                                         \
        const char* hb_ = h8 + ((T_) & 1) * 8192;                              \
        char* hw_ = h8 + (((T_) + 1) & 1) * 8192;                              \
        i32x4 hv[8];                                                           \
        _Pragma("unroll")                                                      \
        for (int kt = 0; kt < 8; ++kt)                                         \
            hv[kt] = *reinterpret_cast<const i32x4*>(                          \
                hb_ + rrow + ((kt * 64 + lq16) ^ swz));                        \
        i32x4 a0 = {0,0,0,0}, a1 = {0,0,0,0}, a2 = {0,0,0,0}, a3 = {0,0,0,0};  \
        _Pragma("unroll")                                                      \
        for (int kt = 0; kt < 8; ++kt) {                                       \
            a0 = MFMA_I8(wq[0][kt], hv[kt], a0);                               \
            a1 = MFMA_I8(wq[1][kt], hv[kt], a1);                               \
        }                                                                      \
        _Pragma("unroll")                                                      \
        for (int kt = 0; kt < 8; ++kt) {                                       \
            a2 = MFMA_I8(wq[2][kt], hv[kt], a2);                               \
            a3 = MFMA_I8(wq[3][kt], hv[kt], a3);                               \
        }                                                                      \
        *reinterpret_cast<unsigned*>(hw_ + wrA[0]) = tq4t(a0, sc2[0], UA.x, UA.y, ttab); \
        *reinterpret_cast<unsigned*>(hw_ + wrA[1]) = tq4t(a1, sc2[1], UA.z, UA.w, ttab); \
        *reinterpret_cast<unsigned*>(hw_ + wrA[2]) = tq4t(a2, sc2[2], UB.x, UB.y, ttab); \
        *reinterpret_cast<unsigned*>(hw_ + wrA[3]) = tq4t(a3, sc2[3], UB.z, UB.w, ttab); \
        __syncthreads();                                                       \
    }

    #pragma unroll 1
    for (int t = 0; t < T_STEPS - 2; t += 2) {
        RSTEP(t, uA0, uB0, uA1, uB1)
        RSTEP(t + 1, uA1, uB1, uA0, uB0)
    }
    RSTEP(T_STEPS - 2, uA0, uB0, uA1, uB1)

    // ---- epilogue t = 2047: precise tanh, f32 store ----
    {
        const char* hb_ = h8 + ((T_STEPS - 1) & 1) * 8192;
        i32x4 a[4] = {{0,0,0,0}, {0,0,0,0}, {0,0,0,0}, {0,0,0,0}};
        #pragma unroll
        for (int kt = 0; kt < 8; ++kt) {
            const i32x4 hv = *reinterpret_cast<const i32x4*>(
                hb_ + rrow + ((kt * 64 + lq16) ^ swz));
            a[0] = MFMA_I8(wq[0][kt], hv, a[0]);
            a[1] = MFMA_I8(wq[1][kt], hv, a[1]);
            a[2] = MFMA_I8(wq[2][kt], hv, a[2]);
            a[3] = MFMA_I8(wq[3][kt], hv, a[3]);
        }
        #pragma unroll
        for (int c = 0; c < 4; ++c) {
            const unsigned w0 = (c == 0) ? uA1.x : (c == 1) ? uA1.z : (c == 2) ? uB1.x : uB1.z;
            const unsigned w1 = (c == 0) ? uA1.y : (c == 1) ? uA1.w : (c == 2) ? uB1.y : uB1.w;
            float th[4];
            #pragma unroll
            for (int r = 0; r < 4; ++r) {
                const unsigned word = (r < 2) ? w0 : w1;
                const float uf = __uint_as_float((r & 1) ? (word & 0xFFFF0000u) : (word << 16));
                const float x2 = fmaf((float)a[c][r], sc2[c][r], uf) * 0.0078125f;
                const float d = __builtin_amdgcn_exp2f(x2) + 1.f;
                th[r] = fmaf(__builtin_amdgcn_rcpf(d), -2.f, 1.f);
            }
            const float4 o = {th[0], th[1], th[2], th[3]};
            *reinterpret_cast<float4*>(out + (size_t)(g * 16 + lr) * HID +
                                       (4 * w + c) * 16 + 4 * lq) = o;
        }
    }
#undef RSTEP
#undef MFMA_I8
}

// ---------------------------------------------------------------------------
extern "C" void kernel_launch(void* const* d_in, const int* in_sizes, int n_in,
                              void* d_out, int out_size, void* d_ws, size_t ws_size,
                              hipStream_t stream) {
    const float* X   = (const float*)d_in[0];   // [2048][64][300]
    const float* Wih = (const float*)d_in[1];   // [512][300]
    const float* Whh = (const float*)d_in[2];   // [512][512]
    const float* bih = (const float*)d_in[3];   // [512]
    const float* bhh = (const float*)d_in[4];   // [512]
    float* out = (float*)d_out;                 // [64][512]
    unsigned short* U3 = (unsigned short*)d_ws; // 128 MB, rec-lane order

    u_gemm<<<dim3(2048 * 8), dim3(256), 0, stream>>>(X, Wih, bih, bhh, U3);
    rnn_rec<<<dim3(4), dim3(512), 0, stream>>>(Whh, U3, out);
}